// Round 6
// baseline (106.859 us; speedup 1.0000x reference)
//
#include <hip/hip_runtime.h>

#define N_NODES 50000
#define N_EDGES 800000
#define D 128

typedef __attribute__((ext_vector_type(8))) short bf16x8;
typedef __attribute__((ext_vector_type(4))) float f32x4;

// ---------------- workspace layout (bytes) ----------------
static const size_t OFF_DEG  = 0;          // int[50000]            (zeroed)
static const size_t OFF_FLAG = 200000;     // int[49] lookback flags (zeroed)
// zero region = [0, 200256) = 12516 int4
static const size_t OFF_PART = 200448;     // int[49] block totals (gated by flags)
static const size_t OFF_OFFS = 200704;     // int[50000]
static const size_t OFF_INV  = 400896;     // float[50000]
static const size_t OFF_WT   = 601088;     // ushort[128*128] bf16 W^T [n][k]
static const size_t OFF_SLOT = 633856;     // ushort[800000]
static const size_t OFF_CSR  = 2233856;    // ushort[800000]
static const size_t OFF_XWB  = 3833856;    // ushort[50000*128] bf16
// total: 16,633,856 bytes

#define SCAN_B 1024
#define SCAN_NB ((N_NODES + SCAN_B - 1) / SCAN_B)   // 49
#define BM 64
#define NB_GEMM ((N_NODES + BM - 1) / BM)           // 782 (each also owns 1024 edges)

__device__ __forceinline__ unsigned short f2bf(float f) {
    unsigned int u = __float_as_uint(f);
    unsigned int r = (u + 0x7fffu + ((u >> 16) & 1u)) >> 16;   // RNE
    return (unsigned short)r;
}
__device__ __forceinline__ float bflo(unsigned int u) { return __uint_as_float(u << 16); }
__device__ __forceinline__ float bfhi(unsigned int u) { return __uint_as_float(u & 0xffff0000u); }

// ---- init: zero deg+flags, convert Wt[n][k] = bf16(W[k][n]) ----
__global__ void k_init(int4* __restrict__ zreg, const float* __restrict__ W,
                       unsigned short* __restrict__ Wt) {
    int bid = blockIdx.x, t = threadIdx.x;
    if (bid < 49) {
        int i = bid * 256 + t;
        if (i < 12516) zreg[i] = make_int4(0, 0, 0, 0);
    } else {
        int idx = (bid - 49) * 256 + t;   // 0..16383
        int n = idx >> 7, k = idx & 127;
        Wt[n * D + k] = f2bf(W[k * D + n]);
    }
}

// ---- fused: every block does GEMM tile + 1024 edges of degree/slot ----
// Atomics issued FIRST (latency hides under staging+MFMA), slots written LAST.
__global__ __launch_bounds__(256) void k_dg(const float* __restrict__ X,
                                            const unsigned short* __restrict__ Wt,
                                            unsigned short* __restrict__ XWb,
                                            const int* __restrict__ dst,
                                            int* __restrict__ deg,
                                            unsigned short* __restrict__ slot) {
    __shared__ unsigned short sA[BM * D];    // 16KB swizzled [row][k]
    __shared__ unsigned short sB[D * D];     // 32KB swizzled [n][k]
    int bid = blockIdx.x;
    int t = threadIdx.x;

    // --- issue edge atomics up front (4 coalesced passes) ---
    int ebase = bid * 1024;
    int e0 = ebase + t, e1 = ebase + 256 + t, e2 = ebase + 512 + t, e3 = ebase + 768 + t;
    int p0 = 0, p1 = 0, p2 = 0, p3 = 0;
    if (e0 < N_EDGES) p0 = atomicAdd(&deg[dst[e0]], 1);
    if (e1 < N_EDGES) p1 = atomicAdd(&deg[dst[e1]], 1);
    if (e2 < N_EDGES) p2 = atomicAdd(&deg[dst[e2]], 1);
    if (e3 < N_EDGES) p3 = atomicAdd(&deg[dst[e3]], 1);

    // --- GEMM tile ---
    int r0 = bid * BM;

    #pragma unroll
    for (int p = 0; p < 8; ++p) {
        int e = p * 2048 + t * 8;
        int n = e >> 7, k = e & 127;
        uint4 v = *(const uint4*)&Wt[e];
        int idx = n * D + (((k >> 3) ^ (n & 7)) << 3);
        *(uint4*)&sB[idx] = v;
    }
    #pragma unroll
    for (int p = 0; p < 8; ++p) {
        int e = p * 1024 + t * 4;
        int r = e >> 7, c = e & 127;
        int row = r0 + r;
        float4 xv = make_float4(0.f, 0.f, 0.f, 0.f);
        if (row < N_NODES) xv = *(const float4*)&X[row * D + c];
        ushort4 bv;
        bv.x = f2bf(xv.x); bv.y = f2bf(xv.y); bv.z = f2bf(xv.z); bv.w = f2bf(xv.w);
        int idx = r * D + (((c >> 3) ^ (r & 7)) << 3) + (c & 7);
        *(ushort4*)&sA[idx] = bv;
    }
    __syncthreads();

    int w = t >> 6, l = t & 63;
    int arow = w * 16 + (l & 15);
    f32x4 acc[8];
    #pragma unroll
    for (int i = 0; i < 8; ++i) acc[i] = (f32x4){0.f, 0.f, 0.f, 0.f};

    #pragma unroll
    for (int kk = 0; kk < 4; ++kk) {
        int g = kk * 4 + (l >> 4);
        bf16x8 a = *(bf16x8*)&sA[arow * D + ((g ^ (arow & 7)) << 3)];
        #pragma unroll
        for (int nt = 0; nt < 8; ++nt) {
            int nrow = nt * 16 + (l & 15);
            bf16x8 b = *(bf16x8*)&sB[nrow * D + ((g ^ (nrow & 7)) << 3)];
            acc[nt] = __builtin_amdgcn_mfma_f32_16x16x32_bf16(a, b, acc[nt], 0, 0, 0);
        }
    }

    #pragma unroll
    for (int nt = 0; nt < 8; ++nt) {
        #pragma unroll
        for (int r = 0; r < 4; ++r) {
            int m = r0 + w * 16 + (l >> 4) * 4 + r;
            if (m < N_NODES) XWb[m * D + nt * 16 + (l & 15)] = f2bf(acc[nt][r]);
        }
    }

    // --- write captured slots (atomic results long since returned) ---
    if (e0 < N_EDGES) slot[e0] = (unsigned short)p0;
    if (e1 < N_EDGES) slot[e1] = (unsigned short)p1;
    if (e2 < N_EDGES) slot[e2] = (unsigned short)p2;
    if (e3 < N_EDGES) slot[e3] = (unsigned short)p3;
}

// ---- single-launch scan (decoupled lookback, 49 co-resident blocks) ----
__global__ __launch_bounds__(1024) void k_scan(const int* __restrict__ deg,
                                               int* __restrict__ part,
                                               int* __restrict__ flag,
                                               int* __restrict__ offs,
                                               float* __restrict__ inv) {
    int b = blockIdx.x;
    int t = threadIdx.x;
    int i = b * SCAN_B + t;
    int v = (i < N_NODES) ? deg[i] : 0;
    int s = v;
    #pragma unroll
    for (int d = 1; d < 64; d <<= 1) {
        int u = __shfl_up(s, d, 64);
        if ((t & 63) >= d) s += u;
    }
    __shared__ int wsum[16];
    __shared__ int s_prefix;
    if ((t & 63) == 63) wsum[t >> 6] = s;
    __syncthreads();
    if (t < 64) {
        int val = (t < 16) ? wsum[t] : 0;
        int sc = val;
        #pragma unroll
        for (int d = 1; d < 16; d <<= 1) {
            int u = __shfl_up(sc, d, 64);
            if (t >= d) sc += u;
        }
        if (t < 16) wsum[t] = sc - val;     // exclusive over waves
        int total = __shfl(sc, 15, 64);     // block total
        if (t == 0) {
            part[b] = total;
            __threadfence();
            atomicExch(&flag[b], 1);
        }
        int pv = 0;
        if (t < b) {
            while (atomicAdd(&flag[t], 0) == 0) { }
        }
        __threadfence();
        if (t < b) pv = atomicAdd(&part[t], 0);
        #pragma unroll
        for (int off = 32; off >= 1; off >>= 1) pv += __shfl_down(pv, off, 64);
        if (t == 0) s_prefix = pv;
    }
    __syncthreads();
    if (i < N_NODES) {
        offs[i] = s - v + wsum[t >> 6] + s_prefix;
        inv[i] = rsqrtf((float)v + 1.0f);
    }
}

// ---- atomic-free CSR fill: 2-byte scatter ----
__global__ void k_fill(const int* __restrict__ src, const int* __restrict__ dst,
                       const int* __restrict__ offs,
                       const unsigned short* __restrict__ slot,
                       unsigned short* __restrict__ csr) {
    int e = blockIdx.x * blockDim.x + threadIdx.x;
    if (e < N_EDGES) {
        csr[offs[dst[e]] + (int)slot[e]] = (unsigned short)src[e];
    }
}

// ---- aggregate (bf16 gather, f32 out), 4-deep gather pipeline ----
__global__ __launch_bounds__(256) void k_agg(const unsigned short* __restrict__ XWb,
                                             const unsigned short* __restrict__ csr,
                                             const int* __restrict__ offs,
                                             const int* __restrict__ deg,
                                             const float* __restrict__ inv,
                                             float* __restrict__ out) {
    int node = blockIdx.x * 4 + (threadIdx.x >> 6);
    if (node >= N_NODES) return;
    int l = threadIdx.x & 63;
    int eg = l >> 4;
    int cl = l & 15;

    int start = offs[node];
    int cnt = deg[node];
    float invd = inv[node];

    float acc[8];
    #pragma unroll
    for (int j = 0; j < 8; ++j) acc[j] = 0.f;

    if (eg == 0) {
        float sl = invd * invd;
        uint4 v = *(const uint4*)&XWb[node * D + cl * 8];
        acc[0] += sl * bflo(v.x); acc[1] += sl * bfhi(v.x);
        acc[2] += sl * bflo(v.y); acc[3] += sl * bfhi(v.y);
        acc[4] += sl * bflo(v.z); acc[5] += sl * bfhi(v.z);
        acc[6] += sl * bflo(v.w); acc[7] += sl * bfhi(v.w);
    }

    for (int e = eg; e < cnt; e += 16) {
        int s[4];
        #pragma unroll
        for (int u = 0; u < 4; ++u) {
            int ee = e + u * 4;
            s[u] = (ee < cnt) ? (int)csr[start + ee] : -1;
        }
        uint4 v[4];
        float nn[4];
        #pragma unroll
        for (int u = 0; u < 4; ++u) {
            int si = (s[u] >= 0) ? s[u] : s[0];
            v[u] = *(const uint4*)&XWb[si * D + cl * 8];
            nn[u] = (s[u] >= 0) ? invd * inv[si] : 0.f;
        }
        #pragma unroll
        for (int u = 0; u < 4; ++u) {
            float n = nn[u];
            acc[0] += n * bflo(v[u].x); acc[1] += n * bfhi(v[u].x);
            acc[2] += n * bflo(v[u].y); acc[3] += n * bfhi(v[u].y);
            acc[4] += n * bflo(v[u].z); acc[5] += n * bfhi(v[u].z);
            acc[6] += n * bflo(v[u].w); acc[7] += n * bfhi(v[u].w);
        }
    }

    #pragma unroll
    for (int j = 0; j < 8; ++j) {
        acc[j] += __shfl_xor(acc[j], 16, 64);
        acc[j] += __shfl_xor(acc[j], 32, 64);
    }

    if (l < 16) {
        float4 v0 = make_float4(acc[0], acc[1], acc[2], acc[3]);
        float4 v1 = make_float4(acc[4], acc[5], acc[6], acc[7]);
        *(float4*)&out[node * D + cl * 8] = v0;
        *(float4*)&out[node * D + cl * 8 + 4] = v1;
    }
}

extern "C" void kernel_launch(void* const* d_in, const int* in_sizes, int n_in,
                              void* d_out, int out_size, void* d_ws, size_t ws_size,
                              hipStream_t stream) {
    const float* X = (const float*)d_in[0];
    const float* W = (const float*)d_in[1];
    const int* esrc = (const int*)d_in[2];
    const int* edst = (const int*)d_in[3];
    float* out = (float*)d_out;

    char* ws = (char*)d_ws;
    int* deg = (int*)(ws + OFF_DEG);
    int* flag = (int*)(ws + OFF_FLAG);
    int* part = (int*)(ws + OFF_PART);
    int* offs = (int*)(ws + OFF_OFFS);
    float* inv = (float*)(ws + OFF_INV);
    unsigned short* Wt = (unsigned short*)(ws + OFF_WT);
    unsigned short* slot = (unsigned short*)(ws + OFF_SLOT);
    unsigned short* csr = (unsigned short*)(ws + OFF_CSR);
    unsigned short* XWb = (unsigned short*)(ws + OFF_XWB);

    k_init<<<113, 256, 0, stream>>>((int4*)(ws + OFF_DEG), W, Wt);
    k_dg<<<NB_GEMM, 256, 0, stream>>>(X, Wt, XWb, edst, deg, slot);
    k_scan<<<SCAN_NB, SCAN_B, 0, stream>>>(deg, part, flag, offs, inv);
    k_fill<<<(N_EDGES + 255) / 256, 256, 0, stream>>>(esrc, edst, offs, slot, csr);
    k_agg<<<(N_NODES + 3) / 4, 256, 0, stream>>>(XWb, csr, offs, deg, inv, out);
}